// Round 2
// baseline (560.830 us; speedup 1.0000x reference)
//
#include <hip/hip_runtime.h>
#include <stdint.h>

#define BB 2
#define SS 2048
#define DMODEL 512
#define NH 8
#define DHD 64

typedef __attribute__((ext_vector_type(8))) short bf16x8;
typedef __attribute__((ext_vector_type(4))) short s16x4;
typedef __attribute__((ext_vector_type(4))) float fx4;

__device__ __forceinline__ short f2bf(float f) {
    union { float f; uint32_t u; } c; c.f = f;
    uint32_t u = c.u;
    u += 0x7fffu + ((u >> 16) & 1u);   // RNE
    return (short)(u >> 16);
}
__device__ __forceinline__ float bf2f(short s) {
    union { uint32_t u; float f; } c; c.u = ((uint32_t)(uint16_t)s) << 16;
    return c.f;
}

// ---------------------------------------------------------------------------
// C = A(4096x512) @ W(512x512) + bias.
// OUT_MODE: 0 = f32 row-major, 1 = bf16 row-major, 2 = bf16 transposed to
//           vT[(b*NH+h)*DHD + d][s]  (B,H,DH,S) for direct PV B-frag loads.
// 64x64 tile, 4 waves, each wave a 32x32 quadrant via 2x2 MFMA 16x16x32 bf16.
// ---------------------------------------------------------------------------
template<int A_BF16, int OUT_MODE>
__global__ __launch_bounds__(256, 4) void gemm_bias_k(
    const void* __restrict__ Ap, const float* __restrict__ W,
    const float* __restrict__ bias, void* __restrict__ Cp)
{
    __shared__ short As[64 * 40];   // [m][k] k-contig, pad 40
    __shared__ short Bs[64 * 40];   // [n][k] (W transposed), pad 40
    const int tid = threadIdx.x;
    const int w = tid >> 6, lane = tid & 63;
    const int cl = lane & 15, quad = lane >> 4;
    const int mi = w >> 1, ni = w & 1;
    const int m0 = blockIdx.x * 64, n0 = blockIdx.y * 64;
    const float* Af = (const float*)Ap;
    const short* Ab = (const short*)Ap;
    fx4 acc[2][2] = {};

    for (int k0 = 0; k0 < DMODEL; k0 += 32) {
        // stage A tile 64x32
#pragma unroll
        for (int it = 0; it < 2; ++it) {
            int idx = tid + it * 256;
            int row = idx >> 3, kq = (idx & 7) * 4;
            s16x4 sv;
            if (A_BF16) {
                sv = *(const s16x4*)&Ab[(size_t)(m0 + row) * DMODEL + k0 + kq];
            } else {
                const float4 vv = *(const float4*)&Af[(size_t)(m0 + row) * DMODEL + k0 + kq];
                sv.x = f2bf(vv.x); sv.y = f2bf(vv.y); sv.z = f2bf(vv.z); sv.w = f2bf(vv.w);
            }
            *(s16x4*)&As[row * 40 + kq] = sv;
        }
        // stage W tile 32x64 transposed -> Bs[n][k]
#pragma unroll
        for (int it = 0; it < 2; ++it) {
            int idx = tid + it * 256;
            int kk = idx >> 4, nq = (idx & 15) * 4;
            const float4 vv = *(const float4*)&W[(size_t)(k0 + kk) * DMODEL + n0 + nq];
            Bs[(nq + 0) * 40 + kk] = f2bf(vv.x);
            Bs[(nq + 1) * 40 + kk] = f2bf(vv.y);
            Bs[(nq + 2) * 40 + kk] = f2bf(vv.z);
            Bs[(nq + 3) * 40 + kk] = f2bf(vv.w);
        }
        __syncthreads();
        bf16x8 af[2], bfr[2];
#pragma unroll
        for (int i = 0; i < 2; ++i)
            af[i] = *(const bf16x8*)&As[(mi * 32 + i * 16 + cl) * 40 + quad * 8];
#pragma unroll
        for (int j = 0; j < 2; ++j)
            bfr[j] = *(const bf16x8*)&Bs[(ni * 32 + j * 16 + cl) * 40 + quad * 8];
#pragma unroll
        for (int i = 0; i < 2; ++i)
#pragma unroll
            for (int j = 0; j < 2; ++j)
                acc[i][j] = __builtin_amdgcn_mfma_f32_16x16x32_bf16(af[i], bfr[j], acc[i][j], 0, 0, 0);
        __syncthreads();
    }
    // epilogue: C/D layout col=lane&15, row=quad*4+reg
#pragma unroll
    for (int i = 0; i < 2; ++i) {
#pragma unroll
        for (int j = 0; j < 2; ++j) {
            int col = n0 + ni * 32 + j * 16 + cl;
            float bv = bias[col];
            if (OUT_MODE == 2) {
                // transposed bf16: rows are contiguous along s -> pack s16x4
                int row0 = m0 + mi * 32 + i * 16 + quad * 4;
                int bb_ = row0 >> 11, sr = row0 & (SS - 1);
                s16x4 o;
                o.x = f2bf(acc[i][j][0] + bv);
                o.y = f2bf(acc[i][j][1] + bv);
                o.z = f2bf(acc[i][j][2] + bv);
                o.w = f2bf(acc[i][j][3] + bv);
                *(s16x4*)&((short*)Cp)[((size_t)(bb_ * DMODEL + col)) * SS + sr] = o;
            } else {
#pragma unroll
                for (int r = 0; r < 4; ++r) {
                    int row = m0 + mi * 32 + i * 16 + quad * 4 + r;
                    float v = acc[i][j][r] + bv;
                    if (OUT_MODE == 1) ((short*)Cp)[(size_t)row * DMODEL + col] = f2bf(v);
                    else               ((float*)Cp)[(size_t)row * DMODEL + col] = v;
                }
            }
        }
    }
}

// ---------------------------------------------------------------------------
// a/b head projections: a[b,h,s] = qp[b,s,:] @ Wa[:,h] + ba[h]   (Wa: 512x8)
// one wave per (b,s) row
// ---------------------------------------------------------------------------
__global__ __launch_bounds__(64) void ab_k(
    const short* __restrict__ qp,
    const float* __restrict__ Wa, const float* __restrict__ ba,
    const float* __restrict__ Wb, const float* __restrict__ bbias,
    float* __restrict__ a_ws, float* __restrict__ b_ws)
{
    const int r = blockIdx.x;
    const int b = r >> 11, s = r & 2047;
    const int lane = threadIdx.x;
    float qv[8];
    s16x4 q0 = *(const s16x4*)&qp[(size_t)r * DMODEL + lane * 8];
    s16x4 q1 = *(const s16x4*)&qp[(size_t)r * DMODEL + lane * 8 + 4];
    qv[0] = bf2f(q0.x); qv[1] = bf2f(q0.y); qv[2] = bf2f(q0.z); qv[3] = bf2f(q0.w);
    qv[4] = bf2f(q1.x); qv[5] = bf2f(q1.y); qv[6] = bf2f(q1.z); qv[7] = bf2f(q1.w);
    float pa[8] = {}, pb[8] = {};
#pragma unroll
    for (int kk = 0; kk < 8; ++kk) {
        int k = lane * 8 + kk;
        const float4 wa0 = *(const float4*)&Wa[k * 8];
        const float4 wa1 = *(const float4*)&Wa[k * 8 + 4];
        const float4 wb0 = *(const float4*)&Wb[k * 8];
        const float4 wb1 = *(const float4*)&Wb[k * 8 + 4];
        float qk = qv[kk];
        pa[0] += qk * wa0.x; pa[1] += qk * wa0.y; pa[2] += qk * wa0.z; pa[3] += qk * wa0.w;
        pa[4] += qk * wa1.x; pa[5] += qk * wa1.y; pa[6] += qk * wa1.z; pa[7] += qk * wa1.w;
        pb[0] += qk * wb0.x; pb[1] += qk * wb0.y; pb[2] += qk * wb0.z; pb[3] += qk * wb0.w;
        pb[4] += qk * wb1.x; pb[5] += qk * wb1.y; pb[6] += qk * wb1.z; pb[7] += qk * wb1.w;
    }
#pragma unroll
    for (int h = 0; h < 8; ++h) {
#pragma unroll
        for (int off = 1; off < 64; off <<= 1) {
            pa[h] += __shfl_xor(pa[h], off);
            pb[h] += __shfl_xor(pb[h], off);
        }
    }
    if (lane == 0) {
#pragma unroll
        for (int h = 0; h < 8; ++h) {
            a_ws[(b * NH + h) * SS + s] = pa[h] + ba[h];
            b_ws[(b * NH + h) * SS + s] = pb[h] + bbias[h];
        }
    }
}

// ---------------------------------------------------------------------------
// Attention. One block per (b,h,16-row q tile). 8 waves (512 thr); wave w owns
// keys [w*256,(w+1)*256). K/V/Q fragments loaded DIRECTLY from global (K slice
// and vT slice are L2-resident); only P transposes through LDS. Scores kept in
// 64 regs/lane, computed in the exp2 domain (log2e folded into coefficients).
// Block swizzle groups all 8 heads of one (b,qtile) onto one XCD back-to-back
// so the shared xdiff panel is fetched from HBM once per XCD pass.
// ---------------------------------------------------------------------------
__global__ __launch_bounds__(512, 4) void attn_k(
    const short* __restrict__ qp, const short* __restrict__ kp, const short* __restrict__ vT,
    const float* __restrict__ a_ws, const float* __restrict__ b_ws,
    const float* __restrict__ xdiff, const int* __restrict__ mask,
    float* __restrict__ attn, short* __restrict__ ao)
{
    __shared__ char smem[32768];          // psw: 8 waves x 16x72 bf16 (18.4KB); reused as ored (32KB)
    __shared__ float redm[128], reds[128];

    const int tid = threadIdx.x;
    const int w = tid >> 6, lane = tid & 63;
    const int cl = lane & 15, quad = lane >> 4;

    // XCD-grouped swizzle: wg = sp*8 + xcd; XCD 'xcd' sees sp ascending, and
    // h = sp&7 cycles fastest within it -> 8 h's sharing one xdiff panel run
    // consecutively on the same XCD's L2.
    const int wg = blockIdx.x;
    const int sp = wg >> 3, xcd = wg & 7;
    const int h = sp & 7;
    const int bqt = xcd * 32 + (sp >> 3);
    const int b = bqt >> 7, qt = bqt & 127;
    const int q0 = qt * 16;
    const int bS = b * SS;

    const float LOG2E = 1.44269504f;

    // Q A-frags direct from global (row = cl, k = kc*32+quad*8)
    bf16x8 qf[2];
#pragma unroll
    for (int kc = 0; kc < 2; ++kc)
        qf[kc] = *(const bf16x8*)&qp[(size_t)(bS + q0 + cl) * DMODEL + h * DHD + kc * 32 + quad * 8];

    float ra[4], rb[4];
#pragma unroll
    for (int r = 0; r < 4; ++r) {
        int qi = q0 + quad * 4 + r;
        ra[r] = a_ws[(b * NH + h) * SS + qi] * LOG2E;
        rb[r] = b_ws[(b * NH + h) * SS + qi] * LOG2E;
    }

    const int j0w = w * 256;
    fx4 s[4][4];
    float rmax[4] = {-3e38f, -3e38f, -3e38f, -3e38f};

    // ---- QK^T + metric terms, scores (log2 domain) in regs ----
#pragma unroll
    for (int t = 0; t < 4; ++t) {
        const int j0 = j0w + t * 64;
        fx4 qk[4] = {};
        __builtin_amdgcn_s_setprio(1);
#pragma unroll
        for (int nb = 0; nb < 4; ++nb)
#pragma unroll
            for (int kc = 0; kc < 2; ++kc) {
                bf16x8 kf = *(const bf16x8*)&kp[(size_t)(bS + j0 + nb * 16 + cl) * DMODEL + h * DHD + kc * 32 + quad * 8];
                qk[nb] = __builtin_amdgcn_mfma_f32_16x16x32_bf16(qf[kc], kf, qk[nb], 0, 0, 0);
            }
        __builtin_amdgcn_s_setprio(0);
#pragma unroll
        for (int nb = 0; nb < 4; ++nb) {
            const int j = j0 + nb * 16 + cl;
            const float mv = -1.442695e9f * (float)mask[bS + j];
#pragma unroll
            for (int r = 0; r < 4; ++r) {
                const int qi = q0 + quad * 4 + r;
                const float xd = xdiff[(size_t)(bS + qi) * SS + j];
                float v = qk[nb][r] * 0.18033688f + mv + ra[r] * xd + rb[r] * (xd * xd);
                s[t][nb][r] = v;
                rmax[r] = fmaxf(rmax[r], v);
            }
        }
    }

    // ---- row max: 16-lane shfl groups, then 8-wave LDS reduce ----
#pragma unroll
    for (int off = 1; off < 16; off <<= 1)
#pragma unroll
        for (int r = 0; r < 4; ++r)
            rmax[r] = fmaxf(rmax[r], __shfl_xor(rmax[r], off));
    if (cl == 0)
#pragma unroll
        for (int r = 0; r < 4; ++r) redm[w * 16 + quad * 4 + r] = rmax[r];
    __syncthreads();
    float gm[4];
#pragma unroll
    for (int r = 0; r < 4; ++r) {
        int i = quad * 4 + r;
        float m0_ = fmaxf(redm[i],      redm[16 + i]);
        float m1_ = fmaxf(redm[32 + i], redm[48 + i]);
        float m2_ = fmaxf(redm[64 + i], redm[80 + i]);
        float m3_ = fmaxf(redm[96 + i], redm[112 + i]);
        gm[r] = fmaxf(fmaxf(m0_, m1_), fmaxf(m2_, m3_));
    }

    // ---- exp2 + row sum ----
    float rsum[4] = {};
#pragma unroll
    for (int t = 0; t < 4; ++t)
#pragma unroll
        for (int nb = 0; nb < 4; ++nb)
#pragma unroll
            for (int r = 0; r < 4; ++r) {
                float e = exp2f(s[t][nb][r] - gm[r]);
                s[t][nb][r] = e;
                rsum[r] += e;
            }
#pragma unroll
    for (int off = 1; off < 16; off <<= 1)
#pragma unroll
        for (int r = 0; r < 4; ++r)
            rsum[r] += __shfl_xor(rsum[r], off);
    if (cl == 0)
#pragma unroll
        for (int r = 0; r < 4; ++r) reds[w * 16 + quad * 4 + r] = rsum[r];
    __syncthreads();
    float gs[4];
#pragma unroll
    for (int r = 0; r < 4; ++r) {
        int i = quad * 4 + r;
        float t0 = reds[i]      + reds[16 + i] + reds[32 + i] + reds[48 + i];
        float t1 = reds[64 + i] + reds[80 + i] + reds[96 + i] + reds[112 + i];
        gs[r] = 1.0f / (t0 + t1);
    }

    // ---- normalize, write attn (nontemporal), PV with direct vT B-frags ----
    fx4 oacc[4] = {};
    float* attn_bh = attn + (size_t)(b * NH + h) * SS * SS;
    short* psw = (short*)smem + w * (16 * 72);
    const size_t vbase = (size_t)((b * NH + h) * DHD) * SS;
#pragma unroll
    for (int t = 0; t < 4; ++t) {
        const int j0 = j0w + t * 64;
#pragma unroll
        for (int nb = 0; nb < 4; ++nb) {
            const int j = j0 + nb * 16 + cl;
#pragma unroll
            for (int r = 0; r < 4; ++r) {
                float p = s[t][nb][r] * gs[r];
                __builtin_nontemporal_store(p, &attn_bh[(size_t)(q0 + quad * 4 + r) * SS + j]);
                psw[(quad * 4 + r) * 72 + nb * 16 + cl] = f2bf(p);
            }
        }
        bf16x8 pf[2];
#pragma unroll
        for (int kc = 0; kc < 2; ++kc)
            pf[kc] = *(const bf16x8*)&psw[cl * 72 + kc * 32 + quad * 8];
        __builtin_amdgcn_s_setprio(1);
#pragma unroll
        for (int nb = 0; nb < 4; ++nb)
#pragma unroll
            for (int kc = 0; kc < 2; ++kc) {
                bf16x8 vf = *(const bf16x8*)&vT[vbase + (size_t)(nb * 16 + cl) * SS + j0 + kc * 32 + quad * 8];
                oacc[nb] = __builtin_amdgcn_mfma_f32_16x16x32_bf16(pf[kc], vf, oacc[nb], 0, 0, 0);
            }
        __builtin_amdgcn_s_setprio(0);
    }

    // ---- cross-wave output reduction (smem reused as fp32 scratch) ----
    __syncthreads();
    float* ored = (float*)smem;
#pragma unroll
    for (int nb = 0; nb < 4; ++nb)
#pragma unroll
        for (int r = 0; r < 4; ++r)
            ored[w * 1024 + (quad * 4 + r) * 64 + nb * 16 + cl] = oacc[nb][r];
    __syncthreads();
    if (tid < 256) {
        int i = tid >> 4, dq = (tid & 15) * 4;
        float sx = 0, sy = 0, sz = 0, sw = 0;
#pragma unroll
        for (int ww = 0; ww < 8; ++ww) {
            const float4 vv = *(const float4*)&ored[ww * 1024 + i * 64 + dq];
            sx += vv.x; sy += vv.y; sz += vv.z; sw += vv.w;
        }
        s16x4 o;
        o.x = f2bf(sx); o.y = f2bf(sy); o.z = f2bf(sz); o.w = f2bf(sw);
        *(s16x4*)&ao[(size_t)(bS + q0 + i) * DMODEL + h * DHD + dq] = o;
    }
}

// ---------------------------------------------------------------------------
extern "C" void kernel_launch(void* const* d_in, const int* in_sizes, int n_in,
                              void* d_out, int out_size, void* d_ws, size_t ws_size,
                              hipStream_t stream)
{
    (void)in_sizes; (void)n_in; (void)out_size; (void)ws_size;
    const float* q     = (const float*)d_in[0];
    const float* k     = (const float*)d_in[1];
    const float* v     = (const float*)d_in[2];
    const float* xdiff = (const float*)d_in[3];
    const int*   mask  = (const int*)d_in[4];
    const float* Wq = (const float*)d_in[5];
    const float* bq = (const float*)d_in[6];
    const float* Wk = (const float*)d_in[7];
    const float* bk = (const float*)d_in[8];
    const float* Wv = (const float*)d_in[9];
    const float* bv = (const float*)d_in[10];
    const float* Wa = (const float*)d_in[11];
    const float* ba = (const float*)d_in[12];
    const float* Wb = (const float*)d_in[13];
    const float* bb = (const float*)d_in[14];
    const float* Wo = (const float*)d_in[15];
    const float* bo = (const float*)d_in[16];

    char* ws = (char*)d_ws;
    short* qp   = (short*)(ws + 0);          // 4096x512 bf16
    short* kp   = (short*)(ws + 4194304);
    short* vT   = (short*)(ws + 8388608);    // (B,H,DH,S) bf16
    float* a_ws = (float*)(ws + 12582912);   // (B,H,S) f32
    float* b_ws = (float*)(ws + 12713984);
    short* ao   = (short*)(ws + 12845056);   // 4096x512 bf16 (attn output pre-Wo)

    float* out  = (float*)d_out;
    float* attn = out + (size_t)BB * SS * DMODEL;

    dim3 g(64, 8), blk(256);
    hipLaunchKernelGGL((gemm_bias_k<0, 1>), g, blk, 0, stream, q, Wq, bq, qp);
    hipLaunchKernelGGL((gemm_bias_k<0, 1>), g, blk, 0, stream, k, Wk, bk, kp);
    hipLaunchKernelGGL((gemm_bias_k<0, 2>), g, blk, 0, stream, v, Wv, bv, vT);
    hipLaunchKernelGGL(ab_k, dim3(4096), dim3(64), 0, stream, qp, Wa, ba, Wb, bb, a_ws, b_ws);
    hipLaunchKernelGGL(attn_k, dim3(2048), dim3(512), 0, stream,
                       qp, kp, vT, a_ws, b_ws, xdiff, mask, attn, ao);
    hipLaunchKernelGGL((gemm_bias_k<1, 0>), g, blk, 0, stream, ao, Wo, bo, out);
}

// Round 3
// 538.779 us; speedup vs baseline: 1.0409x; 1.0409x over previous
//
#include <hip/hip_runtime.h>
#include <stdint.h>

#define BB 2
#define SS 2048
#define DMODEL 512
#define NH 8
#define DHD 64

typedef __attribute__((ext_vector_type(8))) short bf16x8;
typedef __attribute__((ext_vector_type(4))) short s16x4;
typedef __attribute__((ext_vector_type(4))) float fx4;

__device__ __forceinline__ short f2bf(float f) {
    union { float f; uint32_t u; } c; c.f = f;
    uint32_t u = c.u;
    u += 0x7fffu + ((u >> 16) & 1u);   // RNE
    return (short)(u >> 16);
}
__device__ __forceinline__ float bf2f(short s) {
    union { uint32_t u; float f; } c; c.u = ((uint32_t)(uint16_t)s) << 16;
    return c.f;
}

// ---------------------------------------------------------------------------
// Fused QKV projection: z = blockIdx.z selects {q@Wq->qp, k@Wk->kp, v@Wv->vT}.
// C = A(4096x512) @ W(512x512) + bias.  qp/kp: bf16 row-major.
// vT: bf16 transposed to [(b*NH+h)*DHD + d][s] for direct PV B-frag loads.
// 64x64 tile, 4 waves, each wave a 32x32 quadrant via 2x2 MFMA 16x16x32 bf16.
// All three GEMMs resident concurrently (1536 blocks) to hide barrier latency.
// ---------------------------------------------------------------------------
__global__ __launch_bounds__(256, 4) void qkv_gemm_k(
    const float* __restrict__ q, const float* __restrict__ k, const float* __restrict__ v,
    const float* __restrict__ Wq, const float* __restrict__ bq,
    const float* __restrict__ Wk, const float* __restrict__ bk,
    const float* __restrict__ Wv, const float* __restrict__ bv,
    short* __restrict__ qp, short* __restrict__ kp, short* __restrict__ vT)
{
    __shared__ short As[64 * 40];   // [m][k] k-contig, pad 40
    __shared__ short Bs[64 * 40];   // [n][k] (W transposed), pad 40
    const int z = blockIdx.z;
    const float* Af   = (z == 0) ? q  : (z == 1) ? k  : v;
    const float* W    = (z == 0) ? Wq : (z == 1) ? Wk : Wv;
    const float* bias = (z == 0) ? bq : (z == 1) ? bk : bv;
    short* Cp         = (z == 0) ? qp : (z == 1) ? kp : vT;

    const int tid = threadIdx.x;
    const int w = tid >> 6, lane = tid & 63;
    const int cl = lane & 15, quad = lane >> 4;
    const int mi = w >> 1, ni = w & 1;
    const int m0 = blockIdx.x * 64, n0 = blockIdx.y * 64;
    fx4 acc[2][2] = {};

    for (int k0 = 0; k0 < DMODEL; k0 += 32) {
        // stage A tile 64x32
#pragma unroll
        for (int it = 0; it < 2; ++it) {
            int idx = tid + it * 256;
            int row = idx >> 3, kq = (idx & 7) * 4;
            const float4 vv = *(const float4*)&Af[(size_t)(m0 + row) * DMODEL + k0 + kq];
            s16x4 sv;
            sv.x = f2bf(vv.x); sv.y = f2bf(vv.y); sv.z = f2bf(vv.z); sv.w = f2bf(vv.w);
            *(s16x4*)&As[row * 40 + kq] = sv;
        }
        // stage W tile 32x64 transposed -> Bs[n][k]
#pragma unroll
        for (int it = 0; it < 2; ++it) {
            int idx = tid + it * 256;
            int kk = idx >> 4, nq = (idx & 15) * 4;
            const float4 vv = *(const float4*)&W[(size_t)(k0 + kk) * DMODEL + n0 + nq];
            Bs[(nq + 0) * 40 + kk] = f2bf(vv.x);
            Bs[(nq + 1) * 40 + kk] = f2bf(vv.y);
            Bs[(nq + 2) * 40 + kk] = f2bf(vv.z);
            Bs[(nq + 3) * 40 + kk] = f2bf(vv.w);
        }
        __syncthreads();
        bf16x8 af[2], bfr[2];
#pragma unroll
        for (int i = 0; i < 2; ++i)
            af[i] = *(const bf16x8*)&As[(mi * 32 + i * 16 + cl) * 40 + quad * 8];
#pragma unroll
        for (int j = 0; j < 2; ++j)
            bfr[j] = *(const bf16x8*)&Bs[(ni * 32 + j * 16 + cl) * 40 + quad * 8];
#pragma unroll
        for (int i = 0; i < 2; ++i)
#pragma unroll
            for (int j = 0; j < 2; ++j)
                acc[i][j] = __builtin_amdgcn_mfma_f32_16x16x32_bf16(af[i], bfr[j], acc[i][j], 0, 0, 0);
        __syncthreads();
    }
    // epilogue: C/D layout col=lane&15, row=quad*4+reg
#pragma unroll
    for (int i = 0; i < 2; ++i) {
#pragma unroll
        for (int j = 0; j < 2; ++j) {
            int col = n0 + ni * 32 + j * 16 + cl;
            float bv = bias[col];
            if (z == 2) {
                // transposed bf16: 4 consecutive s rows pack into one s16x4
                int row0 = m0 + mi * 32 + i * 16 + quad * 4;
                int bb_ = row0 >> 11, sr = row0 & (SS - 1);
                s16x4 o;
                o.x = f2bf(acc[i][j][0] + bv);
                o.y = f2bf(acc[i][j][1] + bv);
                o.z = f2bf(acc[i][j][2] + bv);
                o.w = f2bf(acc[i][j][3] + bv);
                *(s16x4*)&Cp[((size_t)(bb_ * DMODEL + col)) * SS + sr] = o;
            } else {
#pragma unroll
                for (int r = 0; r < 4; ++r) {
                    int row = m0 + mi * 32 + i * 16 + quad * 4 + r;
                    Cp[(size_t)row * DMODEL + col] = f2bf(acc[i][j][r] + bv);
                }
            }
        }
    }
}

// ---------------------------------------------------------------------------
// Final projection: out = ao(bf16) @ Wo + bo, f32 row-major output.
// ---------------------------------------------------------------------------
__global__ __launch_bounds__(256, 4) void out_gemm_k(
    const short* __restrict__ Ab, const float* __restrict__ W,
    const float* __restrict__ bias, float* __restrict__ Cp)
{
    __shared__ short As[64 * 40];
    __shared__ short Bs[64 * 40];
    const int tid = threadIdx.x;
    const int w = tid >> 6, lane = tid & 63;
    const int cl = lane & 15, quad = lane >> 4;
    const int mi = w >> 1, ni = w & 1;
    const int m0 = blockIdx.x * 64, n0 = blockIdx.y * 64;
    fx4 acc[2][2] = {};

    for (int k0 = 0; k0 < DMODEL; k0 += 32) {
#pragma unroll
        for (int it = 0; it < 2; ++it) {
            int idx = tid + it * 256;
            int row = idx >> 3, kq = (idx & 7) * 4;
            *(s16x4*)&As[row * 40 + kq] =
                *(const s16x4*)&Ab[(size_t)(m0 + row) * DMODEL + k0 + kq];
        }
#pragma unroll
        for (int it = 0; it < 2; ++it) {
            int idx = tid + it * 256;
            int kk = idx >> 4, nq = (idx & 15) * 4;
            const float4 vv = *(const float4*)&W[(size_t)(k0 + kk) * DMODEL + n0 + nq];
            Bs[(nq + 0) * 40 + kk] = f2bf(vv.x);
            Bs[(nq + 1) * 40 + kk] = f2bf(vv.y);
            Bs[(nq + 2) * 40 + kk] = f2bf(vv.z);
            Bs[(nq + 3) * 40 + kk] = f2bf(vv.w);
        }
        __syncthreads();
        bf16x8 af[2], bfr[2];
#pragma unroll
        for (int i = 0; i < 2; ++i)
            af[i] = *(const bf16x8*)&As[(mi * 32 + i * 16 + cl) * 40 + quad * 8];
#pragma unroll
        for (int j = 0; j < 2; ++j)
            bfr[j] = *(const bf16x8*)&Bs[(ni * 32 + j * 16 + cl) * 40 + quad * 8];
#pragma unroll
        for (int i = 0; i < 2; ++i)
#pragma unroll
            for (int j = 0; j < 2; ++j)
                acc[i][j] = __builtin_amdgcn_mfma_f32_16x16x32_bf16(af[i], bfr[j], acc[i][j], 0, 0, 0);
        __syncthreads();
    }
#pragma unroll
    for (int i = 0; i < 2; ++i)
#pragma unroll
        for (int j = 0; j < 2; ++j) {
            int col = n0 + ni * 32 + j * 16 + cl;
            float bv = bias[col];
#pragma unroll
            for (int r = 0; r < 4; ++r) {
                int row = m0 + mi * 32 + i * 16 + quad * 4 + r;
                Cp[(size_t)row * DMODEL + col] = acc[i][j][r] + bv;
            }
        }
}

// ---------------------------------------------------------------------------
// a/b head projections: a[b,h,s] = qp[b,s,:] @ Wa[:,h] + ba[h]   (Wa: 512x8)
// one wave per (b,s) row
// ---------------------------------------------------------------------------
__global__ __launch_bounds__(64) void ab_k(
    const short* __restrict__ qp,
    const float* __restrict__ Wa, const float* __restrict__ ba,
    const float* __restrict__ Wb, const float* __restrict__ bbias,
    float* __restrict__ a_ws, float* __restrict__ b_ws)
{
    const int r = blockIdx.x;
    const int b = r >> 11, s = r & 2047;
    const int lane = threadIdx.x;
    float qv[8];
    s16x4 q0 = *(const s16x4*)&qp[(size_t)r * DMODEL + lane * 8];
    s16x4 q1 = *(const s16x4*)&qp[(size_t)r * DMODEL + lane * 8 + 4];
    qv[0] = bf2f(q0.x); qv[1] = bf2f(q0.y); qv[2] = bf2f(q0.z); qv[3] = bf2f(q0.w);
    qv[4] = bf2f(q1.x); qv[5] = bf2f(q1.y); qv[6] = bf2f(q1.z); qv[7] = bf2f(q1.w);
    float pa[8] = {}, pb[8] = {};
#pragma unroll
    for (int kk = 0; kk < 8; ++kk) {
        int k = lane * 8 + kk;
        const float4 wa0 = *(const float4*)&Wa[k * 8];
        const float4 wa1 = *(const float4*)&Wa[k * 8 + 4];
        const float4 wb0 = *(const float4*)&Wb[k * 8];
        const float4 wb1 = *(const float4*)&Wb[k * 8 + 4];
        float qk = qv[kk];
        pa[0] += qk * wa0.x; pa[1] += qk * wa0.y; pa[2] += qk * wa0.z; pa[3] += qk * wa0.w;
        pa[4] += qk * wa1.x; pa[5] += qk * wa1.y; pa[6] += qk * wa1.z; pa[7] += qk * wa1.w;
        pb[0] += qk * wb0.x; pb[1] += qk * wb0.y; pb[2] += qk * wb0.z; pb[3] += qk * wb0.w;
        pb[4] += qk * wb1.x; pb[5] += qk * wb1.y; pb[6] += qk * wb1.z; pb[7] += qk * wb1.w;
    }
#pragma unroll
    for (int h = 0; h < 8; ++h) {
#pragma unroll
        for (int off = 1; off < 64; off <<= 1) {
            pa[h] += __shfl_xor(pa[h], off);
            pb[h] += __shfl_xor(pb[h], off);
        }
    }
    if (lane == 0) {
#pragma unroll
        for (int h = 0; h < 8; ++h) {
            a_ws[(b * NH + h) * SS + s] = pa[h] + ba[h];
            b_ws[(b * NH + h) * SS + s] = pb[h] + bbias[h];
        }
    }
}

// ---------------------------------------------------------------------------
// Attention. One block per (b,h,16-row q tile). 8 waves (512 thr); wave w owns
// keys [w*256,(w+1)*256). K/V/Q fragments loaded DIRECTLY from global (K slice
// and vT slice are L2-resident); only P transposes through LDS. Scores kept in
// 64 regs/lane, computed in the exp2 domain (log2e folded into coefficients).
// launch_bounds(512,2): 2 blocks/CU -> 4 waves/SIMD, 128-VGPR budget (the
// (512,4) variant capped VGPRs at 64 and spilled the score array: WRITE_SIZE
// +105 MB, VALUBusy 42->20 — measured round 2).
// ---------------------------------------------------------------------------
__global__ __launch_bounds__(512, 2) void attn_k(
    const short* __restrict__ qp, const short* __restrict__ kp, const short* __restrict__ vT,
    const float* __restrict__ a_ws, const float* __restrict__ b_ws,
    const float* __restrict__ xdiff, const int* __restrict__ mask,
    float* __restrict__ attn, short* __restrict__ ao)
{
    __shared__ char smem[32768];          // psw: 8 waves x 16x72 bf16 (18.4KB); reused as ored (32KB)
    __shared__ float redm[128], reds[128];

    const int tid = threadIdx.x;
    const int w = tid >> 6, lane = tid & 63;
    const int cl = lane & 15, quad = lane >> 4;

    // XCD-grouped swizzle: wg = sp*8 + xcd; 8 h's sharing one xdiff panel run
    // consecutively on the same XCD's L2 (FETCH 176->97 MB measured round 2).
    const int wg = blockIdx.x;
    const int sp = wg >> 3, xcd = wg & 7;
    const int h = sp & 7;
    const int bqt = xcd * 32 + (sp >> 3);
    const int b = bqt >> 7, qt = bqt & 127;
    const int q0 = qt * 16;
    const int bS = b * SS;

    const float LOG2E = 1.44269504f;

    // Q A-frags direct from global (row = cl, k = kc*32+quad*8)
    bf16x8 qf[2];
#pragma unroll
    for (int kc = 0; kc < 2; ++kc)
        qf[kc] = *(const bf16x8*)&qp[(size_t)(bS + q0 + cl) * DMODEL + h * DHD + kc * 32 + quad * 8];

    float ra[4], rb[4];
#pragma unroll
    for (int r = 0; r < 4; ++r) {
        int qi = q0 + quad * 4 + r;
        ra[r] = a_ws[(b * NH + h) * SS + qi] * LOG2E;
        rb[r] = b_ws[(b * NH + h) * SS + qi] * LOG2E;
    }

    const int j0w = w * 256;
    fx4 s[4][4];
    float rmax[4] = {-3e38f, -3e38f, -3e38f, -3e38f};

    // ---- QK^T + metric terms, scores (log2 domain) in regs ----
#pragma unroll
    for (int t = 0; t < 4; ++t) {
        const int j0 = j0w + t * 64;
        fx4 qk[4] = {};
        __builtin_amdgcn_s_setprio(1);
#pragma unroll
        for (int nb = 0; nb < 4; ++nb)
#pragma unroll
            for (int kc = 0; kc < 2; ++kc) {
                bf16x8 kf = *(const bf16x8*)&kp[(size_t)(bS + j0 + nb * 16 + cl) * DMODEL + h * DHD + kc * 32 + quad * 8];
                qk[nb] = __builtin_amdgcn_mfma_f32_16x16x32_bf16(qf[kc], kf, qk[nb], 0, 0, 0);
            }
        __builtin_amdgcn_s_setprio(0);
#pragma unroll
        for (int nb = 0; nb < 4; ++nb) {
            const int j = j0 + nb * 16 + cl;
            const float mv = -1.442695e9f * (float)mask[bS + j];
#pragma unroll
            for (int r = 0; r < 4; ++r) {
                const int qi = q0 + quad * 4 + r;
                const float xd = xdiff[(size_t)(bS + qi) * SS + j];
                float v = qk[nb][r] * 0.18033688f + mv + ra[r] * xd + rb[r] * (xd * xd);
                s[t][nb][r] = v;
                rmax[r] = fmaxf(rmax[r], v);
            }
        }
    }

    // ---- row max: 16-lane shfl groups, then 8-wave LDS reduce ----
#pragma unroll
    for (int off = 1; off < 16; off <<= 1)
#pragma unroll
        for (int r = 0; r < 4; ++r)
            rmax[r] = fmaxf(rmax[r], __shfl_xor(rmax[r], off));
    if (cl == 0)
#pragma unroll
        for (int r = 0; r < 4; ++r) redm[w * 16 + quad * 4 + r] = rmax[r];
    __syncthreads();
    float gm[4];
#pragma unroll
    for (int r = 0; r < 4; ++r) {
        int i = quad * 4 + r;
        float m0_ = fmaxf(redm[i],      redm[16 + i]);
        float m1_ = fmaxf(redm[32 + i], redm[48 + i]);
        float m2_ = fmaxf(redm[64 + i], redm[80 + i]);
        float m3_ = fmaxf(redm[96 + i], redm[112 + i]);
        gm[r] = fmaxf(fmaxf(m0_, m1_), fmaxf(m2_, m3_));
    }

    // ---- exp2 + row sum ----
    float rsum[4] = {};
#pragma unroll
    for (int t = 0; t < 4; ++t)
#pragma unroll
        for (int nb = 0; nb < 4; ++nb)
#pragma unroll
            for (int r = 0; r < 4; ++r) {
                float e = exp2f(s[t][nb][r] - gm[r]);
                s[t][nb][r] = e;
                rsum[r] += e;
            }
#pragma unroll
    for (int off = 1; off < 16; off <<= 1)
#pragma unroll
        for (int r = 0; r < 4; ++r)
            rsum[r] += __shfl_xor(rsum[r], off);
    if (cl == 0)
#pragma unroll
        for (int r = 0; r < 4; ++r) reds[w * 16 + quad * 4 + r] = rsum[r];
    __syncthreads();
    float gs[4];
#pragma unroll
    for (int r = 0; r < 4; ++r) {
        int i = quad * 4 + r;
        float t0 = reds[i]      + reds[16 + i] + reds[32 + i] + reds[48 + i];
        float t1 = reds[64 + i] + reds[80 + i] + reds[96 + i] + reds[112 + i];
        gs[r] = 1.0f / (t0 + t1);
    }

    // ---- normalize, write attn (nontemporal), PV with direct vT B-frags ----
    fx4 oacc[4] = {};
    float* attn_bh = attn + (size_t)(b * NH + h) * SS * SS;
    short* psw = (short*)smem + w * (16 * 72);
    const size_t vbase = (size_t)((b * NH + h) * DHD) * SS;
#pragma unroll
    for (int t = 0; t < 4; ++t) {
        const int j0 = j0w + t * 64;
#pragma unroll
        for (int nb = 0; nb < 4; ++nb) {
            const int j = j0 + nb * 16 + cl;
#pragma unroll
            for (int r = 0; r < 4; ++r) {
                float p = s[t][nb][r] * gs[r];
                __builtin_nontemporal_store(p, &attn_bh[(size_t)(q0 + quad * 4 + r) * SS + j]);
                psw[(quad * 4 + r) * 72 + nb * 16 + cl] = f2bf(p);
            }
        }
        bf16x8 pf[2];
#pragma unroll
        for (int kc = 0; kc < 2; ++kc)
            pf[kc] = *(const bf16x8*)&psw[cl * 72 + kc * 32 + quad * 8];
        __builtin_amdgcn_s_setprio(1);
#pragma unroll
        for (int nb = 0; nb < 4; ++nb)
#pragma unroll
            for (int kc = 0; kc < 2; ++kc) {
                bf16x8 vf = *(const bf16x8*)&vT[vbase + (size_t)(nb * 16 + cl) * SS + j0 + kc * 32 + quad * 8];
                oacc[nb] = __builtin_amdgcn_mfma_f32_16x16x32_bf16(pf[kc], vf, oacc[nb], 0, 0, 0);
            }
        __builtin_amdgcn_s_setprio(0);
    }

    // ---- cross-wave output reduction (smem reused as fp32 scratch) ----
    __syncthreads();
    float* ored = (float*)smem;
#pragma unroll
    for (int nb = 0; nb < 4; ++nb)
#pragma unroll
        for (int r = 0; r < 4; ++r)
            ored[w * 1024 + (quad * 4 + r) * 64 + nb * 16 + cl] = oacc[nb][r];
    __syncthreads();
    if (tid < 256) {
        int i = tid >> 4, dq = (tid & 15) * 4;
        float sx = 0, sy = 0, sz = 0, sw = 0;
#pragma unroll
        for (int ww = 0; ww < 8; ++ww) {
            const float4 vv = *(const float4*)&ored[ww * 1024 + i * 64 + dq];
            sx += vv.x; sy += vv.y; sz += vv.z; sw += vv.w;
        }
        s16x4 o;
        o.x = f2bf(sx); o.y = f2bf(sy); o.z = f2bf(sz); o.w = f2bf(sw);
        *(s16x4*)&ao[(size_t)(bS + q0 + i) * DMODEL + h * DHD + dq] = o;
    }
}

// ---------------------------------------------------------------------------
extern "C" void kernel_launch(void* const* d_in, const int* in_sizes, int n_in,
                              void* d_out, int out_size, void* d_ws, size_t ws_size,
                              hipStream_t stream)
{
    (void)in_sizes; (void)n_in; (void)out_size; (void)ws_size;
    const float* q     = (const float*)d_in[0];
    const float* k     = (const float*)d_in[1];
    const float* v     = (const float*)d_in[2];
    const float* xdiff = (const float*)d_in[3];
    const int*   mask  = (const int*)d_in[4];
    const float* Wq = (const float*)d_in[5];
    const float* bq = (const float*)d_in[6];
    const float* Wk = (const float*)d_in[7];
    const float* bk = (const float*)d_in[8];
    const float* Wv = (const float*)d_in[9];
    const float* bv = (const float*)d_in[10];
    const float* Wa = (const float*)d_in[11];
    const float* ba = (const float*)d_in[12];
    const float* Wb = (const float*)d_in[13];
    const float* bb = (const float*)d_in[14];
    const float* Wo = (const float*)d_in[15];
    const float* bo = (const float*)d_in[16];

    char* ws = (char*)d_ws;
    short* qp   = (short*)(ws + 0);          // 4096x512 bf16
    short* kp   = (short*)(ws + 4194304);
    short* vT   = (short*)(ws + 8388608);    // (B,H,DH,S) bf16
    float* a_ws = (float*)(ws + 12582912);   // (B,H,S) f32
    float* b_ws = (float*)(ws + 12713984);
    short* ao   = (short*)(ws + 12845056);   // 4096x512 bf16 (attn output pre-Wo)

    float* out  = (float*)d_out;
    float* attn = out + (size_t)BB * SS * DMODEL;

    hipLaunchKernelGGL(qkv_gemm_k, dim3(64, 8, 3), dim3(256), 0, stream,
                       q, k, v, Wq, bq, Wk, bk, Wv, bv, qp, kp, vT);
    hipLaunchKernelGGL(ab_k, dim3(4096), dim3(64), 0, stream, qp, Wa, ba, Wb, bb, a_ws, b_ws);
    hipLaunchKernelGGL(attn_k, dim3(2048), dim3(512), 0, stream,
                       qp, kp, vT, a_ws, b_ws, xdiff, mask, attn, ao);
    hipLaunchKernelGGL(out_gemm_k, dim3(64, 8), dim3(256), 0, stream, ao, Wo, bo, out);
}